// Round 10
// baseline (24.106 us; speedup 1.0000x reference)
//
#include <hip/hip_runtime.h>
#include <math.h>

#define KFEAT 32768
#define GRID_N 33                // 33x33 grid, step = 1/32 of domain
#define NPTS (GRID_N * GRID_N)   // 1089 (LDS Fs size; odd-odd entries unused)
#define NQ 833                   // live points: NOT (odd gx & odd gy)
#define QSTRIDE 836              // NQ padded to multiple of 4
#define QGROUPS (QSTRIDE / 4)    // 209 float4 groups per split row
#define NRP 17                   // row pairs (rp 16 = final even row only)
#define SPLITK 32
#define KPT 4                    // k's per thread = KFEAT / SPLITK / 256

#define INV2PI 0.15915494309189535f

// cos(2*pi*rev): v_fract (exact range reduction by periodicity) + v_cos
// (input in revolutions).
__device__ __forceinline__ float cos_rev(float rev) {
  float fr, c;
  asm("v_fract_f32 %0, %1" : "=v"(fr) : "v"(rev));
  asm("v_cos_f32 %0, %1" : "=v"(c) : "v"(fr));
  return c;
}

// ---------------------------------------------------------------------------
// Kernel 1 (row-recurrence eval): block = (row-pair rp, K-split). Each thread
// owns KPT=4 k's. Per k and per row, theta(gx) = base + gx*delta is
// arithmetic, so the weighted cosine d_n = w*cos(theta_n) follows
// d_{n+1} = 2cos(delta)*d_n - d_{n-1}: 1 fma + 1 add per point instead of
// 2 fma + fract + cos + fma. 5 transcendentals per (k, row-pair), amortized
// over 50 points (cos(2delta) = 2cos^2(delta)-1 is free).
// Output layout matches the q-compaction: q = rp*50 + rem; rem<33 -> even row
// gx=rem; rem>=33 -> odd row gx=2*(rem-33).
// ---------------------------------------------------------------------------
__global__ __launch_bounds__(256) void eval_rows_kernel(
    const float4* __restrict__ w4, const float4* __restrict__ ax4,
    const float4* __restrict__ ay4, const float4* __restrict__ phi4,
    const float* __restrict__ xa_p, const float* __restrict__ xb_p,
    const float* __restrict__ ya_p, const float* __restrict__ yb_p,
    float* __restrict__ Fpart) {
  const int tid = threadIdx.x;
  const int rp = blockIdx.x;      // row pair 0..16
  const int split = blockIdx.y;   // 0..31
  const float xa = xa_p[0], xb = xb_p[0];
  const float ya = ya_p[0], yb = yb_p[0];
  const float sx = (xb - xa) * (1.0f / 32.0f);
  const float sy = (yb - ya) * (1.0f / 32.0f);
  const float ye = fmaf((float)(2 * rp), sy, ya);  // even row y

  // One float4 per array: k's [4*idx, 4*idx+4).
  const int idx = split * (KFEAT / 4 / SPLITK) + tid;  // split*256 + tid
  float4 A4 = ax4[idx], B4 = ay4[idx], P4 = phi4[idx], W4 = w4[idx];
  const float Aa[4] = {A4.x * INV2PI, A4.y * INV2PI, A4.z * INV2PI,
                       A4.w * INV2PI};
  const float Ba[4] = {B4.x * INV2PI, B4.y * INV2PI, B4.z * INV2PI,
                       B4.w * INV2PI};
  const float Pa[4] = {P4.x * INV2PI, P4.y * INV2PI, P4.z * INV2PI,
                       P4.w * INV2PI};
  const float Wa[4] = {W4.x, W4.y, W4.z, W4.w};

  float acc[50];
#pragma unroll
  for (int j = 0; j < 50; ++j) acc[j] = 0.0f;

#pragma unroll
  for (int kk = 0; kk < KPT; ++kk) {
    const float Ar = Aa[kk], Br = Ba[kk], Pr = Pa[kk], W = Wa[kk];
    const float dr = Ar * sx;            // delta (revolutions)
    const float cb = cos_rev(dr);        // cos(delta)
    const float twob = cb + cb;
    const float base = fmaf(Ar, xa, fmaf(Br, ye, Pr));
    // even row: gx = 0..32, stride delta
    {
      float d0 = W * cos_rev(base);
      float d1 = W * cos_rev(base + dr);
      acc[0] += d0;
      acc[1] += d1;
#pragma unroll
      for (int n = 2; n < 33; ++n) {
        float dn = fmaf(twob, d1, -d0);
        acc[n] += dn;
        d0 = d1;
        d1 = dn;
      }
    }
    // odd row (rp<16 only): gx = 0,2,..,32, stride 2*delta
    if (rp < 16) {
      const float c2b = fmaf(twob, cb, -1.0f);  // cos(2delta)
      const float two2 = c2b + c2b;
      const float baseo = fmaf(Br, sy, base);   // y + sy
      float e0 = W * cos_rev(baseo);
      float e1 = W * cos_rev(baseo + dr + dr);
      acc[33] += e0;
      acc[34] += e1;
#pragma unroll
      for (int g = 2; g < 17; ++g) {
        float en = fmaf(two2, e1, -e0);
        acc[33 + g] += en;
        e0 = e1;
        e1 = en;
      }
    }
  }

  // Reduce 50 accumulators across the 256-thread block.
  __shared__ float red[4][50];
#pragma unroll
  for (int j = 0; j < 50; ++j) {
    float v = acc[j];
#pragma unroll
    for (int off = 32; off > 0; off >>= 1) v += __shfl_down(v, off, 64);
    if ((tid & 63) == 0) red[tid >> 6][j] = v;
  }
  __syncthreads();
  const int npts = (rp < 16) ? 50 : 33;
  if (tid < npts) {
    float v = red[0][tid] + red[1][tid] + red[2][tid] + red[3][tid];
    Fpart[split * QSTRIDE + rp * 50 + tid] = v;
  }
}

// ---------------------------------------------------------------------------
// Kernel 2: sum 32 split rows (836 tasks x 8 independent float4 loads ->
// quad partials in LDS; merge + scatter q->(gy*33+gx)), then Simpson cells
// at depths 0..4 + adaptive tree combine. Cell index uses the reference's
// interleaved quadrant order (base-4 digits, MSB = depth 1): ix = even bits
// compacted, iy = odd bits compacted (Morton).
// ---------------------------------------------------------------------------
__device__ __forceinline__ int compact_bits(int v, int shift) {
  int r = (v >> shift) & 1;
  r |= ((v >> (shift + 2)) & 1) << 1;
  r |= ((v >> (shift + 4)) & 1) << 2;
  r |= ((v >> (shift + 6)) & 1) << 3;
  return r;
}

__device__ __forceinline__ float simpson_cell(const float* __restrict__ F,
                                              int d, int cell, float hx,
                                              float hy) {
  const int ix = compact_bits(cell, 0);
  const int iy = compact_bits(cell, 1);
  const int s = 5 - d;        // log2 of cell size in grid units
  const int h = 1 << (s - 1); // half-cell in grid units
  const int gx0 = ix << s, gx1 = gx0 + h, gx2 = gx0 + 2 * h;
  const int gy0 = iy << s, gy1 = gy0 + h, gy2 = gy0 + 2 * h;
  // point order: 0:(xl,yl) 1:(mx,yl) 2:(xr,yl) 3:(xl,my) 4:(xr,my)
  //              5:(xl,yr) 6:(mx,yr) 7:(xr,yr)  (center (gx1,gy1), the only
  // (odd,odd) point, has coefficient 0 in the reference formula -- skipped)
  const float f0 = F[gy0 * GRID_N + gx0];
  const float f1 = F[gy0 * GRID_N + gx1];
  const float f2 = F[gy0 * GRID_N + gx2];
  const float f3 = F[gy1 * GRID_N + gx0];
  const float f4 = F[gy1 * GRID_N + gx2];
  const float f5 = F[gy2 * GRID_N + gx0];
  const float f6 = F[gy2 * GRID_N + gx1];
  const float f7 = F[gy2 * GRID_N + gx2];
  return hx * hy * (1.0f / 12.0f) *
         (-(f0 + f2 + f5 + f7) + 4.0f * (f1 + f3 + f4 + f6));
}

__global__ __launch_bounds__(256) void combine_kernel(
    const float* __restrict__ Fpart, const float* __restrict__ xa_p,
    const float* __restrict__ xb_p, const float* __restrict__ ya_p,
    const float* __restrict__ yb_p, const float* __restrict__ eps_p,
    float* __restrict__ out) {
  __shared__ alignas(16) float Fq[4][QSTRIDE];  // quad partial sums
  __shared__ float Fs[NPTS];   // grid-indexed; (odd,odd) entries never read
  __shared__ float S4[256], S3[64], S2[16], S1[4], S0[1];
  __shared__ float val3[64], val2[16], val1[4];
  const int t = threadIdx.x;
  const float xa = *xa_p, xb = *xb_p, ya = *ya_p, yb = *yb_p, eps = *eps_p;
  const float HX = fabsf(xb - xa), HY = fabsf(yb - ya);

  // --- stage 1: 836 tasks; task = g*4 + quad; each sums 8 split rows ---
  const float4* Fp4 = (const float4*)Fpart;
  for (int task = t; task < 4 * QGROUPS; task += 256) {
    const int g = task >> 2;
    const int quad = task & 3;
    float4 s = make_float4(0.0f, 0.0f, 0.0f, 0.0f);
#pragma unroll
    for (int sp = 0; sp < 8; ++sp) {
      float4 v = Fp4[(quad * 8 + sp) * QGROUPS + g];
      s.x += v.x; s.y += v.y; s.z += v.z; s.w += v.w;
    }
    ((float4*)&Fq[quad][0])[g] = s;  // pad floats (q>=833) garbage; never read
  }
  __syncthreads();

  // --- stage 2: merge quads + scatter compacted q -> grid position ---
  for (int q = t; q < NQ; q += 256) {
    float v = (Fq[0][q] + Fq[1][q]) + (Fq[2][q] + Fq[3][q]);
    int rp = q / 50;
    int rem = q - 50 * rp;
    int gx, gy;
    if (rem < 33) { gy = 2 * rp;     gx = rem; }
    else          { gy = 2 * rp + 1; gx = (rem - 33) * 2; }
    Fs[gy * GRID_N + gx] = v;
  }
  __syncthreads();

  // --- Simpson estimates at every depth ---
  S4[t] = simpson_cell(Fs, 4, t, HX * 0.0625f, HY * 0.0625f);
  if (t < 64) {
    S3[t] = simpson_cell(Fs, 3, t, HX * 0.125f, HY * 0.125f);
  } else if (t < 80) {
    S2[t - 64] = simpson_cell(Fs, 2, t - 64, HX * 0.25f, HY * 0.25f);
  } else if (t < 84) {
    S1[t - 80] = simpson_cell(Fs, 1, t - 80, HX * 0.5f, HY * 0.5f);
  } else if (t == 84) {
    S0[0] = simpson_cell(Fs, 0, 0, HX, HY);
  }
  __syncthreads();

  // --- d = 3 (MAX_DEPTH-1): truncate -> corrected unconditionally ---
  if (t < 64) {
    float sumq = ((S4[4 * t] + S4[4 * t + 1]) + S4[4 * t + 2]) + S4[4 * t + 3];
    // reference bug reproduced: quadrant 3 'whole' is quadrant 0's S
    float whole = ((t & 3) == 3) ? S3[t & ~3] : S3[t];
    float delta = sumq - whole;
    val3[t] = sumq + delta * (1.0f / 15.0f);
  }
  __syncthreads();

  // --- d = 2 ---
  if (t < 16) {
    float sumq = ((S3[4 * t] + S3[4 * t + 1]) + S3[4 * t + 2]) + S3[4 * t + 3];
    float whole = ((t & 3) == 3) ? S2[t & ~3] : S2[t];
    float delta = sumq - whole;
    float corrected = sumq + delta * (1.0f / 15.0f);
    float child =
        ((val3[4 * t] + val3[4 * t + 1]) + val3[4 * t + 2]) + val3[4 * t + 3];
    float eps_d = eps * (1.0f / 16.0f);  // eps / 4^2
    val2[t] = (fabsf(delta) <= 15.0f * eps_d) ? corrected : child;
  }
  __syncthreads();

  // --- d = 1 ---
  if (t < 4) {
    float sumq = ((S2[4 * t] + S2[4 * t + 1]) + S2[4 * t + 2]) + S2[4 * t + 3];
    float whole = ((t & 3) == 3) ? S1[t & ~3] : S1[t];
    float delta = sumq - whole;
    float corrected = sumq + delta * (1.0f / 15.0f);
    float child =
        ((val2[4 * t] + val2[4 * t + 1]) + val2[4 * t + 2]) + val2[4 * t + 3];
    float eps_d = eps * 0.25f;  // eps / 4^1
    val1[t] = (fabsf(delta) <= 15.0f * eps_d) ? corrected : child;
  }
  __syncthreads();

  // --- d = 0 ---
  if (t == 0) {
    float sumq = ((S1[0] + S1[1]) + S1[2]) + S1[3];
    float delta = sumq - S0[0];
    float corrected = sumq + delta * (1.0f / 15.0f);
    float child = ((val1[0] + val1[1]) + val1[2]) + val1[3];
    out[0] = (fabsf(delta) <= 15.0f * eps) ? corrected : child;
  }
}

extern "C" void kernel_launch(void* const* d_in, const int* in_sizes, int n_in,
                              void* d_out, int out_size, void* d_ws,
                              size_t ws_size, hipStream_t stream) {
  // input order: xa, xb, ya, yb, eps, w, ax, ay, phi
  const float* xa = (const float*)d_in[0];
  const float* xb = (const float*)d_in[1];
  const float* ya = (const float*)d_in[2];
  const float* yb = (const float*)d_in[3];
  const float* eps = (const float*)d_in[4];
  const float4* w4 = (const float4*)d_in[5];
  const float4* ax4 = (const float4*)d_in[6];
  const float4* ay4 = (const float4*)d_in[7];
  const float4* phi4 = (const float4*)d_in[8];
  float* out = (float*)d_out;
  float* Fpart = (float*)d_ws;  // SPLITK * QSTRIDE floats (107008 B)

  dim3 grid(NRP, SPLITK);
  eval_rows_kernel<<<grid, 256, 0, stream>>>(w4, ax4, ay4, phi4, xa, xb, ya,
                                             yb, Fpart);
  combine_kernel<<<1, 256, 0, stream>>>(Fpart, xa, xb, ya, yb, eps, out);
}